// Round 4
// baseline (150.630 us; speedup 1.0000x reference)
//
#include <hip/hip_runtime.h>

// SigMMDLoss, fully flattened (see earlier rounds for derivation):
//   per-row: A = p[4095]-p[0]; S3 = p[4095] - SP_row/n; S4 = (A^2+S6)/2;
//            S6 = sum d^2; S8 = sum d^3;  time-only features cancel.
// Linear global sums (signed real - gen), computed in the STREAM kernel:
//   SPall = sum p (all cols), D2 = sum d^2, D3 = sum d^3
// Nonlinear / edge sums, computed in the tiny EDGE kernel (cols 0 & 4095):
//   G1 = sum_rows A, G2 = sum_rows A^2, G3 = sum_rows p[4095]
// Finalize: SP_excl = SPall - G3;
//   FA=G1/B; FS3=(G3 - SP_excl/n)/B; FS4=.5(G2+D2)/B; FS6=D2/B; FS8=D3/B
//   out = sum F^2.
//
// Round-4 point: hot kernel is a pure flat read-stream — no shuffles, no
// serial carry, no per-row reductions, 8 loads in flight, low VGPR.

constexpr int T_LEN = 4096;
constexpr int B_ROWS = 4096;
constexpr int F4_PER_ARRAY = B_ROWS * T_LEN / 4;      // 4,194,304
constexpr int THREADS_TOTAL = 2 * F4_PER_ARRAY / 4;   // 2,097,152
constexpr int NBLK = THREADS_TOTAL / 256;             // 8192
constexpr int EDGE_BLK = 32;
// ws layout: [3][NBLK] main partials, then [3][EDGE_BLK] edge partials
constexpr int EDGE_OFF = 3 * NBLK;

__global__ __launch_bounds__(256) void sig_stream(const float* __restrict__ real,
                                                  const float* __restrict__ gen,
                                                  double* __restrict__ P) {
  const int tid0 = blockIdx.x * 256 + threadIdx.x;

  float4 a[4];
  float s[4];
  int col4[4];
  // Issue all 8 loads up front (4x float4 + 4x seam scalar).
#pragma unroll
  for (int i = 0; i < 4; ++i) {
    const float* base = (i < 2) ? real : gen;
    const int f = tid0 + (i & 1) * THREADS_TOTAL;     // float4 index in array
    col4[i] = f & (T_LEN / 4 - 1);                    // 0..1023
    a[i] = reinterpret_cast<const float4*>(base)[f];
    const int sidx = 4 * f + ((col4[i] < 1023) ? 4 : 0);  // clamp at row end
    s[i] = base[sidx];
  }

  float asp = 0.f, as2 = 0.f, as3 = 0.f;
#pragma unroll
  for (int i = 0; i < 4; ++i) {
    const float sg = (i < 2) ? 1.f : -1.f;
    const float d1 = a[i].y - a[i].x;
    const float d2 = a[i].z - a[i].y;
    const float d3 = a[i].w - a[i].z;
    const float d0 = (col4[i] < 1023) ? (s[i] - a[i].w) : 0.f;  // seam diff
    const float e0 = d0 * d0, e1 = d1 * d1, e2 = d2 * d2, e3 = d3 * d3;
    asp += sg * ((a[i].x + a[i].y) + (a[i].z + a[i].w));
    as2 += sg * ((e0 + e1) + (e2 + e3));
    as3 += sg * ((e0 * d0 + e1 * d1) + (e2 * d2 + e3 * d3));
  }

  // Wave reduce (fp32), then block reduce in LDS (double).
#pragma unroll
  for (int off = 32; off; off >>= 1) {
    asp += __shfl_down(asp, off, 64);
    as2 += __shfl_down(as2, off, 64);
    as3 += __shfl_down(as3, off, 64);
  }
  __shared__ double sred[4][3];
  const int lane = threadIdx.x & 63, wid = threadIdx.x >> 6;
  if (lane == 0) {
    sred[wid][0] = (double)asp;
    sred[wid][1] = (double)as2;
    sred[wid][2] = (double)as3;
  }
  __syncthreads();
  if (threadIdx.x < 3) {
    const double v = sred[0][threadIdx.x] + sred[1][threadIdx.x] +
                     sred[2][threadIdx.x] + sred[3][threadIdx.x];
    P[threadIdx.x * NBLK + blockIdx.x] = v;
  }
}

__global__ __launch_bounds__(256) void sig_edge(const float* __restrict__ real,
                                                const float* __restrict__ gen,
                                                double* __restrict__ P) {
  const int r = blockIdx.x * 256 + threadIdx.x;      // 0..8191
  const int which = r >> 12;
  const int row = r & (B_ROWS - 1);
  const float* p = (which ? gen : real) + (size_t)row * T_LEN;
  const float pf = p[0];
  const float pl = p[T_LEN - 1];
  const double sg = which ? -1.0 : 1.0;
  const double A = (double)pl - (double)pf;
  double g1 = sg * A, g2 = sg * A * A, g3 = sg * (double)pl;

#pragma unroll
  for (int off = 32; off; off >>= 1) {
    g1 += __shfl_down(g1, off, 64);
    g2 += __shfl_down(g2, off, 64);
    g3 += __shfl_down(g3, off, 64);
  }
  __shared__ double sred[4][3];
  const int lane = threadIdx.x & 63, wid = threadIdx.x >> 6;
  if (lane == 0) { sred[wid][0] = g1; sred[wid][1] = g2; sred[wid][2] = g3; }
  __syncthreads();
  if (threadIdx.x < 3) {
    const double v = sred[0][threadIdx.x] + sred[1][threadIdx.x] +
                     sred[2][threadIdx.x] + sred[3][threadIdx.x];
    P[EDGE_OFF + threadIdx.x * EDGE_BLK + blockIdx.x] = v;
  }
}

__global__ __launch_bounds__(256) void sig_final(const double* __restrict__ P,
                                                 float* __restrict__ out) {
  const int tid = threadIdx.x;
  double loc[3] = {0, 0, 0};
  for (int i = tid; i < NBLK; i += 256)
#pragma unroll
    for (int q = 0; q < 3; ++q) loc[q] += P[q * NBLK + i];
  double ge[3] = {0, 0, 0};
  if (tid < EDGE_BLK)
#pragma unroll
    for (int q = 0; q < 3; ++q) ge[q] = P[EDGE_OFF + q * EDGE_BLK + tid];

#pragma unroll
  for (int off = 32; off; off >>= 1)
#pragma unroll
    for (int q = 0; q < 3; ++q) {
      loc[q] += __shfl_down(loc[q], off, 64);
      ge[q] += __shfl_down(ge[q], off, 64);
    }
  __shared__ double sred[4][6];
  const int lane = tid & 63, wid = tid >> 6;
  if (lane == 0)
#pragma unroll
    for (int q = 0; q < 3; ++q) {
      sred[wid][q] = loc[q];
      sred[wid][3 + q] = ge[q];
    }
  __syncthreads();
  if (tid == 0) {
    double Q[6];
#pragma unroll
    for (int q = 0; q < 6; ++q)
      Q[q] = sred[0][q] + sred[1][q] + sred[2][q] + sred[3][q];
    const double SPall = Q[0], D2 = Q[1], D3 = Q[2];
    const double G1 = Q[3], G2 = Q[4], G3 = Q[5];
    const double n = (double)(T_LEN - 1), Bn = (double)B_ROWS;
    const double SPex = SPall - G3;
    const double FA = G1 / Bn;
    const double FS3 = (G3 - SPex / n) / Bn;
    const double FS4 = 0.5 * (G2 + D2) / Bn;
    const double FS6 = D2 / Bn;
    const double FS8 = D3 / Bn;
    out[0] = (float)(FA * FA + FS3 * FS3 + FS4 * FS4 + FS6 * FS6 + FS8 * FS8);
  }
}

extern "C" void kernel_launch(void* const* d_in, const int* in_sizes, int n_in,
                              void* d_out, int out_size, void* d_ws, size_t ws_size,
                              hipStream_t stream) {
  const float* real = (const float*)d_in[0];
  const float* gen = (const float*)d_in[1];
  double* P = (double*)d_ws;   // (3*8192 + 3*32) * 8 = ~197 KB
  float* out = (float*)d_out;

  sig_stream<<<NBLK, 256, 0, stream>>>(real, gen, P);
  sig_edge<<<EDGE_BLK, 256, 0, stream>>>(real, gen, P);
  sig_final<<<1, 256, 0, stream>>>(P, out);
}